// Round 1
// baseline (76.193 us; speedup 1.0000x reference)
//
#include <hip/hip_runtime.h>
#include <hip/hip_bf16.h>

// Problem constants (S4Layer: T=4096, B=16, D=128, S=256)
#define T_  4096
#define B_  16
#define D_  128
#define S_  256
#define TCM 128            // M-tile (t rows) per GEMM block
#define SN  64             // N-tile (s cols) per GEMM block
#define C2  (T_/TCM)       // 32 GEMM chunks
#define WND 32             // scan chunk length
#define C4  (T_/WND)       // 128 scan chunks

using bf8   = __attribute__((ext_vector_type(8))) short;   // 8 bf16 (4 VGPRs)
using f32x4 = __attribute__((ext_vector_type(4))) float;   // MFMA acc

__device__ inline unsigned short f2bf(float f) {
    unsigned u = __builtin_bit_cast(unsigned, f);
    u += 0x7fffu + ((u >> 16) & 1u);           // RNE
    return (unsigned short)(u >> 16);
}
__device__ inline float bf2f(unsigned short h) {
    return __builtin_bit_cast(float, (unsigned)h << 16);
}

// ---------------- K1: parameters -------------------------------------------
// a_bar[S], a_pow[j][S] for j=0..32, b_bar[S][D] in bf16
__global__ __launch_bounds__(256) void k_params(
        const float* __restrict__ lna, const float* __restrict__ bmat,
        const float* __restrict__ ldt,
        float* __restrict__ abar, float* __restrict__ apow,
        unsigned short* __restrict__ bbar) {
    int s = threadIdx.x;
    float la = fminf(fmaxf(lna[s], -8.f), 4.f);
    float ar = -expf(la);
    float lt = fminf(fmaxf(ldt[s], -8.f), 1.f);
    float dt = expf(lt);
    float x  = dt * ar;
    float ab = expf(x);
    float ratio = (fabsf(x) < 1e-6f) ? dt : (expm1f(x) / ar);
    abar[s] = ab;
    float p = 1.f;
    for (int j = 0; j <= WND; ++j) { apow[j * S_ + s] = p; p *= ab; }
    for (int d = 0; d < D_; ++d) bbar[s * D_ + d] = f2bf(ratio * bmat[s * D_ + d]);
}

// ---------------- K2: GEMM (bf16 MFMA) + window end-states -----------------
// ub[t,b,s] (bf16) = sum_d x[t,b,d]*b_bar[s,d];  e64[c4,b,s] = sum_j a^(31-j) ub[c4*32+j]
__global__ __launch_bounds__(256, 1) void k_gemm(
        const float* __restrict__ x, const short* __restrict__ bbar,
        const float* __restrict__ apow,
        unsigned short* __restrict__ ub, float* __restrict__ e64) {
    const int c2 = blockIdx.x, b = blockIdx.y, st = blockIdx.z;
    const int t0 = c2 * TCM, n0 = st * SN;
    __shared__ char  Als[TCM * 256];   // [128 rows][128 bf16] XOR-swizzled, 32 KiB
    __shared__ float Els[4][SN];
    const int tid = threadIdx.x, lane = tid & 63, wid = tid >> 6;
    const int l15 = lane & 15, l4 = lane >> 4;
    const int mh = wid >> 1, nh = wid & 1;   // 2x2 wave grid: 64 t x 32 s per wave

    // B fragments straight from global (L2-resident, reused by all blocks)
    bf8 bfrag[2][4];
#pragma unroll
    for (int j = 0; j < 2; ++j) {
        int s = n0 + nh * 32 + j * 16 + l15;
#pragma unroll
        for (int kk = 0; kk < 4; ++kk)
            bfrag[j][kk] = *(const bf8*)(bbar + s * D_ + kk * 32 + l4 * 8);
    }
    // Stage A tile: fp32 global -> bf16 LDS, XOR swizzle (G4: stride-256B rows)
    for (int idx = tid; idx < TCM * 32; idx += 256) {
        int row = idx >> 5, seg = idx & 31;
        float4 v = *(const float4*)(x + ((size_t)(t0 + row) * B_ + b) * D_ + seg * 4);
        short4 h;
        h.x = (short)f2bf(v.x); h.y = (short)f2bf(v.y);
        h.z = (short)f2bf(v.z); h.w = (short)f2bf(v.w);
        int off = (row * 256 + seg * 8) ^ ((row & 7) << 4);
        *(short4*)(Als + off) = h;
    }
    __syncthreads();

    f32x4 acc[4][2] = {};
#pragma unroll
    for (int i = 0; i < 4; ++i) {
        bf8 af[4];
        int tr = mh * 64 + i * 16 + l15;
#pragma unroll
        for (int kk = 0; kk < 4; ++kk) {
            int off = (tr * 256 + kk * 64 + l4 * 16) ^ ((tr & 7) << 4);
            af[kk] = *(const bf8*)(Als + off);
        }
#pragma unroll
        for (int j = 0; j < 2; ++j)
#pragma unroll
            for (int kk = 0; kk < 4; ++kk)
                acc[i][j] = __builtin_amdgcn_mfma_f32_16x16x32_bf16(
                                af[kk], bfrag[j][kk], acc[i][j], 0, 0, 0);
    }

    // Epilogue: store ub (bf16) + weighted window end-state partials
    float e[2][2] = {{0.f, 0.f}, {0.f, 0.f}};
#pragma unroll
    for (int i = 0; i < 4; ++i) {
#pragma unroll
        for (int j = 0; j < 2; ++j) {
            int s = n0 + nh * 32 + j * 16 + l15;
#pragma unroll
            for (int r = 0; r < 4; ++r) {
                int t = t0 + mh * 64 + i * 16 + l4 * 4 + r;   // C/D: row=(l>>4)*4+reg
                float v = acc[i][j][r];
                ub[((size_t)t * B_ + b) * S_ + s] = f2bf(v);
                int jj = (i & 1) * 16 + l4 * 4 + r;           // t within 32-window
                e[i >> 1][j] = fmaf(apow[(WND - 1 - jj) * S_ + s], v, e[i >> 1][j]);
            }
        }
    }
#pragma unroll
    for (int w = 0; w < 2; ++w)
#pragma unroll
        for (int j = 0; j < 2; ++j) {
            float v = e[w][j];
            v += __shfl_xor(v, 16);
            v += __shfl_xor(v, 32);
            if (l4 == 0) Els[mh * 2 + w][nh * 32 + j * 16 + l15] = v;
        }
    __syncthreads();
    {   // 4 windows x 64 s = 256 values, one per thread
        int w = tid >> 6, sl = tid & 63;
        e64[((size_t)(c2 * 4 + w) * B_ + b) * S_ + n0 + sl] = Els[w][sl];
    }
}

// ---------------- K3: carry scan across 128 chunks -------------------------
__global__ __launch_bounds__(256) void k_carry(
        const float* __restrict__ e64, const float* __restrict__ apow,
        const float* __restrict__ z0, float* __restrict__ cin) {
    int b = blockIdx.x, s = threadIdx.x;
    float a32 = apow[WND * S_ + s];
    float Z = z0[b * S_ + s];
    for (int c = 0; c < C4; ++c) {
        cin[((size_t)c * B_ + b) * S_ + s] = Z;
        Z = fmaf(a32, Z, e64[((size_t)c * B_ + b) * S_ + s]);
    }
}

// ---------------- K4: per-chunk scan + output ------------------------------
__global__ __launch_bounds__(256) void k_scan(
        const unsigned short* __restrict__ ub, const float* __restrict__ cin,
        const float* __restrict__ abar, float* __restrict__ out) {
    int c4 = blockIdx.x, b = blockIdx.y, s = threadIdx.x;
    float a = abar[s];
    float z = cin[((size_t)c4 * B_ + b) * S_ + s];
    size_t base = ((size_t)(c4 * WND) * B_ + b) * S_ + s;
#pragma unroll
    for (int j = 0; j < WND; ++j) {
        z = fmaf(a, z, bf2f(ub[base]));
        out[base] = z;
        base += (size_t)B_ * S_;
    }
}

extern "C" void kernel_launch(void* const* d_in, const int* in_sizes, int n_in,
                              void* d_out, int out_size, void* d_ws, size_t ws_size,
                              hipStream_t stream) {
    const float* x   = (const float*)d_in[0];  // [T,B,D]
    const float* z0  = (const float*)d_in[1];  // [B,S]
    const float* lna = (const float*)d_in[2];  // [S]
    const float* bm  = (const float*)d_in[3];  // [S,D]
    const float* ldt = (const float*)d_in[4];  // [S]
    float* out = (float*)d_out;

    char* ws = (char*)d_ws;
    float*          abar = (float*)ws;                                  // 1 KiB
    float*          apow = (float*)(ws + 1024);                         // 33 KiB
    float*          e64  = (float*)(ws + (64 << 10));                   // 2 MiB
    float*          cin  = (float*)(ws + (64 << 10) + (2 << 20));       // 2 MiB
    short*          bbar = (short*)(ws + (64 << 10) + (4 << 20));       // 64 KiB
    unsigned short* ub   = (unsigned short*)(ws + (8 << 20));           // 32 MiB

    k_params<<<1, 256, 0, stream>>>(lna, bm, ldt, abar, apow, (unsigned short*)bbar);
    k_gemm<<<dim3(C2, B_, S_ / SN), 256, 0, stream>>>(x, bbar, apow, ub, e64);
    k_carry<<<B_, 256, 0, stream>>>(e64, apow, z0, cin);
    k_scan<<<dim3(C4, B_), 256, 0, stream>>>(ub, cin, abar, out);
}

// Round 2
// 55.669 us; speedup vs baseline: 1.3687x; 1.3687x over previous
//
#include <hip/hip_runtime.h>
#include <hip/hip_bf16.h>

// Problem constants (S4Layer: T=4096, B=16, D=128, S=256)
#define T_  4096
#define B_  16
#define D_  128
#define S_  256
#define TCM 128            // M-tile (t rows) per GEMM block
#define C2  (T_/TCM)       // 32 GEMM tiles along T
#define WND 64             // scan chunk length
#define C4  (T_/WND)       // 64 scan chunks

using bf8   = __attribute__((ext_vector_type(8))) short;   // 8 bf16 (4 VGPRs)
using f32x4 = __attribute__((ext_vector_type(4))) float;   // MFMA acc

// ---------------- K1: parameters -------------------------------------------
// blocks 0..127: bbar[s][d] = ratio[s]*b[s][d] in bf16 ;  block 128: abar, a^64
__global__ __launch_bounds__(256) void k_params(
        const float* __restrict__ lna, const float* __restrict__ bmat,
        const float* __restrict__ ldt,
        float* __restrict__ abar, float* __restrict__ a64,
        __hip_bfloat16* __restrict__ bbar) {
    if (blockIdx.x < 128) {
        int idx = blockIdx.x * 256 + threadIdx.x;   // (s,d)
        int s = idx >> 7;
        float la = fminf(fmaxf(lna[s], -8.f), 4.f);
        float ar = -expf(la);
        float lt = fminf(fmaxf(ldt[s], -8.f), 1.f);
        float dt = expf(lt);
        float xx = dt * ar;
        float ratio = (fabsf(xx) < 1e-6f) ? dt : (expm1f(xx) / ar);
        bbar[idx] = __float2bfloat16(ratio * bmat[idx]);
    } else {
        int s = threadIdx.x;
        float la = fminf(fmaxf(lna[s], -8.f), 4.f);
        float ar = -expf(la);
        float lt = fminf(fmaxf(ldt[s], -8.f), 1.f);
        float dt = expf(lt);
        float ab = expf(dt * ar);
        abar[s] = ab;
        float p = ab;
#pragma unroll
        for (int j = 0; j < 6; ++j) p *= p;     // a^64 by squaring
        a64[s] = p;
    }
}

// ---------------- K2: GEMM (bf16 MFMA) + window end-states -----------------
// ub[b,t,s] (bf16) = sum_d x[t,b,d]*b_bar[s,d];  e64[c,b,s] = sum_j a^(63-j) ub[c*64+j]
// 256 thr = 4 waves (2 mh x 2 nh), wave tile 64t x 64s; s-halves looped (st).
__global__ __launch_bounds__(256) void k_gemm(
        const float* __restrict__ x, const __hip_bfloat16* __restrict__ bbar,
        const float* __restrict__ abar,
        __hip_bfloat16* __restrict__ ub, float* __restrict__ e64) {
    const int c2 = blockIdx.x, b = blockIdx.y;
    const int t0 = c2 * TCM;
    __shared__ char  Als[TCM * 256];   // [128 t][128 bf16] XOR-swizzled, 32 KiB
    __shared__ float Els[2][128];
    const int tid = threadIdx.x, lane = tid & 63, wid = tid >> 6;
    const int l15 = lane & 15, l4 = lane >> 4;
    const int mh = wid >> 1, nh = wid & 1;

    // Stage A tile once: fp32 global -> bf16 LDS, XOR swizzle (G4)
    for (int idx = tid; idx < TCM * 32; idx += 256) {
        int row = idx >> 5, seg = idx & 31;
        float4 v = *(const float4*)(x + ((size_t)(t0 + row) * B_ + b) * D_ + seg * 4);
        __hip_bfloat162 lo = __float22bfloat162_rn(make_float2(v.x, v.y));
        __hip_bfloat162 hi = __float22bfloat162_rn(make_float2(v.z, v.w));
        uint2 pk = { *(unsigned*)&lo, *(unsigned*)&hi };
        int off = (row * 256 + seg * 8) ^ ((row & 7) << 4);
        *(uint2*)(Als + off) = pk;
    }
    __syncthreads();

    for (int st = 0; st < 2; ++st) {
        const int n0 = st * 128;
        bf8 bfrag[4][4];
#pragma unroll
        for (int j = 0; j < 4; ++j) {
            int s = n0 + nh * 64 + j * 16 + l15;
#pragma unroll
            for (int kk = 0; kk < 4; ++kk)
                bfrag[j][kk] = *(const bf8*)((const short*)bbar + s * D_ + kk * 32 + l4 * 8);
        }
        f32x4 acc[4][4] = {};
#pragma unroll
        for (int i = 0; i < 4; ++i) {
            bf8 af[4];
            int tr = mh * 64 + i * 16 + l15;
#pragma unroll
            for (int kk = 0; kk < 4; ++kk) {
                int off = (tr * 256 + kk * 64 + l4 * 16) ^ ((tr & 7) << 4);
                af[kk] = *(const bf8*)(Als + off);
            }
#pragma unroll
            for (int j = 0; j < 4; ++j)
#pragma unroll
                for (int kk = 0; kk < 4; ++kk)
                    acc[i][j] = __builtin_amdgcn_mfma_f32_16x16x32_bf16(
                                    af[kk], bfrag[j][kk], acc[i][j], 0, 0, 0);
        }

        // Epilogue: ub stores + Horner-weighted window end-state.
        // weight a^(63-jj), jj = i*16 + l4*4 + r  =>  a^(12-4*l4) * a^(48-16i) * a^(3-r)
#pragma unroll
        for (int j = 0; j < 4; ++j) {
            int s = n0 + nh * 64 + j * 16 + l15;
            float a  = abar[s];
            float a2 = a * a, a4 = a2 * a2, a8 = a4 * a4, a16 = a8 * a8;
            float lf = (l4 == 0) ? a8 * a4 : (l4 == 1) ? a8 : (l4 == 2) ? a4 : 1.f;
            float e = 0.f;
#pragma unroll
            for (int i = 0; i < 4; ++i) {
                float inner = acc[i][j][0];
                inner = fmaf(inner, a, acc[i][j][1]);
                inner = fmaf(inner, a, acc[i][j][2]);
                inner = fmaf(inner, a, acc[i][j][3]);
                e = fmaf(e, a16, inner);
                int t = t0 + mh * 64 + i * 16 + l4 * 4;     // C/D: row=(l>>4)*4+r
                size_t ob = ((size_t)b * T_ + t) * S_ + s;
#pragma unroll
                for (int r = 0; r < 4; ++r)
                    ub[ob + (size_t)r * S_] = __float2bfloat16(acc[i][j][r]);
            }
            e *= lf;
            e += __shfl_xor(e, 16);
            e += __shfl_xor(e, 32);
            if (l4 == 0) Els[mh][nh * 64 + j * 16 + l15] = e;
        }
        __syncthreads();
        {   // 2 windows x 128 s = 256 values, one per thread
            int w = tid >> 7, sl = tid & 127;
            e64[((size_t)(c2 * 2 + w) * B_ + b) * S_ + n0 + sl] = Els[w][sl];
        }
        if (st == 0) __syncthreads();   // Els reused next iteration
    }
}

// ---------------- K3: carry scan across 64 chunks --------------------------
__global__ __launch_bounds__(256) void k_carry(
        const float* __restrict__ e64, const float* __restrict__ a64,
        const float* __restrict__ z0, float* __restrict__ cin) {
    int b = blockIdx.x, s = threadIdx.x;
    float aw = a64[s];
    float Z = z0[b * S_ + s];
    for (int c = 0; c < C4; ++c) {
        cin[((size_t)c * B_ + b) * S_ + s] = Z;
        Z = fmaf(aw, Z, e64[((size_t)c * B_ + b) * S_ + s]);
    }
}

// ---------------- K4: per-chunk scan + output ------------------------------
__global__ __launch_bounds__(256) void k_scan(
        const __hip_bfloat16* __restrict__ ub, const float* __restrict__ cin,
        const float* __restrict__ abar, float* __restrict__ out) {
    int c4 = blockIdx.x, b = blockIdx.y, s = threadIdx.x;
    float a = abar[s];
    float z = cin[((size_t)c4 * B_ + b) * S_ + s];
    const __hip_bfloat16* up = ub + ((size_t)b * T_ + c4 * WND) * S_ + s;
    float* op = out + ((size_t)(c4 * WND) * B_ + b) * S_ + s;
#pragma unroll 8
    for (int j = 0; j < WND; ++j) {
        z = fmaf(a, z, __bfloat162float(*up));
        *op = z;
        up += S_;
        op += (size_t)B_ * S_;
    }
}

extern "C" void kernel_launch(void* const* d_in, const int* in_sizes, int n_in,
                              void* d_out, int out_size, void* d_ws, size_t ws_size,
                              hipStream_t stream) {
    const float* x   = (const float*)d_in[0];  // [T,B,D]
    const float* z0  = (const float*)d_in[1];  // [B,S]
    const float* lna = (const float*)d_in[2];  // [S]
    const float* bm  = (const float*)d_in[3];  // [S,D]
    const float* ldt = (const float*)d_in[4];  // [S]
    float* out = (float*)d_out;

    char* ws = (char*)d_ws;
    float*          abar = (float*)ws;                          // 1 KiB
    float*          a64  = (float*)(ws + 4096);                 // 1 KiB
    __hip_bfloat16* bbar = (__hip_bfloat16*)(ws + 8192);        // 64 KiB
    float*          e64  = (float*)(ws + (128 << 10));          // 1 MiB
    float*          cin  = (float*)(ws + (128 << 10) + (1 << 20)); // 1 MiB
    __hip_bfloat16* ub   = (__hip_bfloat16*)(ws + (4 << 20));   // 32 MiB, [b][t][s]

    k_params<<<129, 256, 0, stream>>>(lna, bm, ldt, abar, a64, bbar);
    k_gemm<<<dim3(C2, B_), 256, 0, stream>>>(x, bbar, abar, ub, e64);
    k_carry<<<B_, 256, 0, stream>>>(e64, a64, z0, cin);
    k_scan<<<dim3(C4, B_), 256, 0, stream>>>(ub, cin, abar, out);
}